// Round 7
// baseline (658.907 us; speedup 1.0000x reference)
//
#include <hip/hip_runtime.h>
#include <stdint.h>

#define NH 16
#define HD 64
#define DM 1024
#define BB 2
#define LL 2048

typedef __bf16 bf16x8 __attribute__((ext_vector_type(8)));
typedef float f32x4 __attribute__((ext_vector_type(4)));

__device__ __forceinline__ uint16_t f2bf(float f) {
  union { float f; uint32_t u; } x{f};
  uint32_t r = (x.u + 0x7fff + ((x.u >> 16) & 1)) >> 16;
  return (uint16_t)r;
}
__device__ __forceinline__ float bf2f(uint16_t u) {
  union { uint32_t u; float f; } x{(uint32_t)u << 16};
  return x.f;
}

__device__ __forceinline__ void gload_lds16(const void* g, void* l) {
  __builtin_amdgcn_global_load_lds(
      (const __attribute__((address_space(1))) unsigned int*)g,
      (__attribute__((address_space(3))) unsigned int*)l, 16, 0, 0);
}

// ---------------- fp32 -> bf16 cast (same layout)
__global__ __launch_bounds__(256) void cvt_bf16(
    const float* __restrict__ x, uint16_t* __restrict__ y, int n4) {
  int i = blockIdx.x * 256 + threadIdx.x;
  if (i >= n4) return;
  float4 v = ((const float4*)x)[i];
  ushort4 o;
  o.x = f2bf(v.x); o.y = f2bf(v.y); o.z = f2bf(v.z); o.w = f2bf(v.w);
  ((ushort4*)y)[i] = o;
}

// ---------------- fp32 [K,N] -> bf16 [N,K] transpose-cast
__global__ __launch_bounds__(256) void transpose_cvt(
    const float* __restrict__ W, uint16_t* __restrict__ WT, int K, int N) {
  __shared__ float t[32][33];
  int bk = blockIdx.y * 32, bn = blockIdx.x * 32;
  int c = threadIdx.x & 31, r0 = threadIdx.x >> 5;
#pragma unroll
  for (int p = 0; p < 4; ++p) {
    int r = r0 + p * 8;
    t[r][c] = W[(size_t)(bk + r) * N + bn + c];
  }
  __syncthreads();
#pragma unroll
  for (int p = 0; p < 4; ++p) {
    int r = r0 + p * 8;
    WT[(size_t)(bn + r) * K + bk + c] = f2bf(t[c][r]);
  }
}

// ---------------- bf16 MFMA GEMM: C = A @ BT^T + bias; fp32 or bf16 output
__global__ __launch_bounds__(256) void gemm_bt_bf16(
    const uint16_t* __restrict__ A, const uint16_t* __restrict__ BT,
    const float* __restrict__ bias, void* __restrict__ Cout, int c_bf16,
    int M, int N, int K) {
  __shared__ uint16_t As[128 * 32];
  __shared__ uint16_t Bs[128 * 32];
  const int tid = threadIdx.x;
  const int bm = blockIdx.y * 128, bn = blockIdx.x * 128;
  const int lane = tid & 63, wave = tid >> 6;
  const int wr = wave >> 1, wc = wave & 1;
  f32x4 acc[4][4] = {};

  for (int k0 = 0; k0 < K; k0 += 32) {
#pragma unroll
    for (int c = 0; c < 2; ++c) {
      int e = c * 2048 + tid * 8;
      int r = e >> 5, col = e & 31;
      gload_lds16(A + (size_t)(bm + r) * K + k0 + col, (char*)As + (size_t)e * 2);
      gload_lds16(BT + (size_t)(bn + r) * K + k0 + col, (char*)Bs + (size_t)e * 2);
    }
    __syncthreads();

    const int kseg = (lane >> 4) * 8;
    bf16x8 af[4], bfr[4];
#pragma unroll
    for (int i = 0; i < 4; ++i)
      af[i] = *(const bf16x8*)&As[(wr * 64 + i * 16 + (lane & 15)) * 32 + kseg];
#pragma unroll
    for (int j = 0; j < 4; ++j)
      bfr[j] = *(const bf16x8*)&Bs[(wc * 64 + j * 16 + (lane & 15)) * 32 + kseg];
#pragma unroll
    for (int i = 0; i < 4; ++i)
#pragma unroll
      for (int j = 0; j < 4; ++j)
        acc[i][j] = __builtin_amdgcn_mfma_f32_16x16x32_bf16(af[i], bfr[j], acc[i][j], 0, 0, 0);
    __syncthreads();
  }

#pragma unroll
  for (int i = 0; i < 4; ++i) {
#pragma unroll
    for (int j = 0; j < 4; ++j) {
      int col = bn + wc * 64 + j * 16 + (lane & 15);
      float bv = bias[col];
#pragma unroll
      for (int r = 0; r < 4; ++r) {
        size_t row = (size_t)(bm + wr * 64 + i * 16 + (lane >> 4) * 4 + r);
        float v = acc[i][j][r] + bv;
        if (c_bf16)
          ((uint16_t*)Cout)[row * N + col] = f2bf(v);
        else
          ((float*)Cout)[row * N + col] = v;
      }
    }
  }
}

// ---------------- attention compute: probs band (bf16, d_ws) + ctx (bf16)
// Per block: 32 q-rows, 160-key window (kbase = q0-128 for qt>=4, else 0).
// LDS 38.4 KB -> 4 blocks/CU.
#define QT 32
#define KT 160
#define KS 72    // Qs/Ksb row stride (bf16)
#define PS 168   // Sf/Psb row stride

__global__ __launch_bounds__(256, 4) void attn_compute(
    const uint16_t* __restrict__ qkvb,  // [B*L, 3*DM] bf16
    uint16_t* __restrict__ band,        // [2048][32][160] bf16 probs
    uint16_t* __restrict__ ctxb,        // [B*L, DM] bf16
    const int* __restrict__ wsz_p) {
  __shared__ __align__(16) char smemU[KT * KS * 2];     // Ksb (bf16) / Sf (f32)
  __shared__ __align__(16) uint16_t Qs[QT * KS];
  __shared__ __align__(16) uint16_t Psb[QT * PS];
  uint16_t* Ksb = (uint16_t*)smemU;
  float* Sf = (float*)smemU;

  const int wsz = *wsz_p;  // 128
  const int tid = threadIdx.x;
  const int lane = tid & 63, wave = tid >> 6;
  const int ntile = LL / QT;
  const int qt = blockIdx.x % ntile;
  const int h = (blockIdx.x / ntile) % NH;
  const int b = blockIdx.x / (ntile * NH);
  const int q0 = qt * QT;
  const int kbase = max(0, q0 - (wsz - 1)) & ~31;  // = q0-128 (qt>=4) or 0

  // ---- P0: stage Q (32x64) and K (160x64), bf16 16B units
  if (tid < 256) {
    int r = tid >> 3, c8 = (tid & 7) * 8;
    *(bf16x8*)&Qs[r * KS + c8] =
        *(const bf16x8*)&qkvb[(size_t)(b * LL + q0 + r) * (3 * DM) + h * HD + c8];
  }
#pragma unroll
  for (int p = 0; p < 5; ++p) {
    int u = tid + p * 256;
    if (u < KT * 8) {
      int r = u >> 3, c8 = (u & 7) * 8;
      *(bf16x8*)&Ksb[r * KS + c8] =
          *(const bf16x8*)&qkvb[(size_t)(b * LL + kbase + r) * (3 * DM) + DM + h * HD + c8];
    }
  }
  __syncthreads();

  // ---- P1a: S = Q K^T fragments. wave w: m-tile w&1, n-tiles (w>>1)*5..+5
  const int mt = wave & 1, ntb = (wave >> 1) * 5;
  f32x4 sfrag[5];
  {
    const int kseg = (lane >> 4) * 8;
    bf16x8 aq0 = *(const bf16x8*)&Qs[(mt * 16 + (lane & 15)) * KS + kseg];
    bf16x8 aq1 = *(const bf16x8*)&Qs[(mt * 16 + (lane & 15)) * KS + 32 + kseg];
#pragma unroll
    for (int t = 0; t < 5; ++t) {
      int nt = ntb + t;
      bf16x8 bk0 = *(const bf16x8*)&Ksb[(nt * 16 + (lane & 15)) * KS + kseg];
      bf16x8 bk1 = *(const bf16x8*)&Ksb[(nt * 16 + (lane & 15)) * KS + 32 + kseg];
      f32x4 c = {0.f, 0.f, 0.f, 0.f};
      c = __builtin_amdgcn_mfma_f32_16x16x32_bf16(aq0, bk0, c, 0, 0, 0);
      c = __builtin_amdgcn_mfma_f32_16x16x32_bf16(aq1, bk1, c, 0, 0, 0);
      sfrag[t] = c;
    }
  }
  __syncthreads();  // Ksb done; Sf may overwrite union

  // ---- P1b: spill S to Sf (fp32)
#pragma unroll
  for (int t = 0; t < 5; ++t) {
    int nt = ntb + t;
#pragma unroll
    for (int r = 0; r < 4; ++r)
      Sf[(mt * 16 + (lane >> 4) * 4 + r) * PS + nt * 16 + (lane & 15)] = sfrag[t][r];
  }
  __syncthreads();

  // ---- P2: softmax (octet per q-row); probs -> Psb (bf16)
  {
    const int qi = tid >> 3;
    const int kg = tid & 7;
    const int q = q0 + qi;
    float s[20];
#pragma unroll
    for (int j = 0; j < 20; ++j) s[j] = Sf[qi * PS + kg + 8 * j];
    float m = -1e30f;
#pragma unroll
    for (int j = 0; j < 20; ++j) {
      int gk = kbase + kg + 8 * j;
      bool valid = (gk <= q) && (gk > q - wsz);
      s[j] = valid ? s[j] * 0.125f : -1e30f;
      m = fmaxf(m, s[j]);
    }
#pragma unroll
    for (int off = 1; off < 8; off <<= 1)
      m = fmaxf(m, __shfl_xor(m, off, 64));
    float l = 0.f;
#pragma unroll
    for (int j = 0; j < 20; ++j) {
      float e = (s[j] > -1e29f) ? __expf(s[j] - m) : 0.f;
      s[j] = e;
      l += e;
    }
#pragma unroll
    for (int off = 1; off < 8; off <<= 1)
      l += __shfl_xor(l, off, 64);
    float inv = 1.f / l;
#pragma unroll
    for (int j = 0; j < 20; ++j)
      Psb[qi * PS + kg + 8 * j] = f2bf(s[j] * inv);
  }
  __syncthreads();

  // ---- P3: dump prob band -> d_ws (bf16, contiguous, 1x-amp memory)
#pragma unroll
  for (int p = 0; p < 3; ++p) {
    int u = tid + p * 256;
    if (u < QT * KT / 8) {            // 640 16B-units
      int r = u / 20, c8 = (u % 20) * 8;
      *(bf16x8*)(band + (size_t)blockIdx.x * (QT * KT) + (size_t)u * 8) =
          *(const bf16x8*)&Psb[r * PS + c8];
    }
  }

  // ---- P4: O = P V via MFMA; V gathered from global bf16
  {
    const int nt = wave;
    const int kseg = (lane >> 4) * 8;
    f32x4 ofrag[2] = {};
#pragma unroll
    for (int ks = 0; ks < 5; ++ks) {
      const uint16_t* vs = qkvb + (size_t)(b * LL + kbase + ks * 32 + kseg) * (3 * DM) +
                           2 * DM + h * HD + nt * 16 + (lane & 15);
      uint16_t vb[8];
#pragma unroll
      for (int j = 0; j < 8; ++j) vb[j] = vs[(size_t)j * (3 * DM)];
      bf16x8 bv = *(const bf16x8*)vb;
#pragma unroll
      for (int m = 0; m < 2; ++m) {
        bf16x8 ap = *(const bf16x8*)&Psb[(m * 16 + (lane & 15)) * PS + ks * 32 + kseg];
        ofrag[m] = __builtin_amdgcn_mfma_f32_16x16x32_bf16(ap, bv, ofrag[m], 0, 0, 0);
      }
    }
#pragma unroll
    for (int m = 0; m < 2; ++m)
#pragma unroll
      for (int r = 0; r < 4; ++r) {
        int q = q0 + m * 16 + (lane >> 4) * 4 + r;
        ctxb[(size_t)(b * LL + q) * DM + h * HD + nt * 16 + (lane & 15)] = f2bf(ofrag[m][r]);
      }
  }
}

// ---------------- expander: band (bf16) -> full attnw rows (fp32, nt stores)
// Pure write-stream kernel: 10 KB LDS -> 8 blocks/CU, 32 waves/CU of store
// pressure. One block per (b,h,qtile): writes 32 rows x 2048 cols.
__global__ __launch_bounds__(256) void expand_attnw(
    const uint16_t* __restrict__ band, float* __restrict__ attnw,
    const int* __restrict__ wsz_p) {
  __shared__ __align__(16) uint16_t Pb[QT * KT];  // 10240 B
  const int wsz = *wsz_p;
  const int tid = threadIdx.x;
  const int ntile = LL / QT;
  const int qt = blockIdx.x % ntile;
  const int h = (blockIdx.x / ntile) % NH;
  const int b = blockIdx.x / (ntile * NH);
  const int q0 = qt * QT;
  const int kbase = max(0, q0 - (wsz - 1)) & ~31;

#pragma unroll
  for (int p = 0; p < 3; ++p) {
    int u = tid + p * 256;
    if (u < QT * KT / 8)
      *(bf16x8*)&Pb[u * 8] =
          *(const bf16x8*)(band + (size_t)blockIdx.x * (QT * KT) + (size_t)u * 8);
  }
  __syncthreads();

#pragma unroll
  for (int it = 0; it < 16; ++it) {
    int r = it * 2 + (tid >> 7);
    size_t rowoff = ((size_t)((b * NH + h) * LL + q0 + r)) * LL;
    int cb = (tid & 127) * 4;
#pragma unroll
    for (int jj = 0; jj < 4; ++jj) {
      int c4 = cb + jj * 512;
      f32x4 v = {0.f, 0.f, 0.f, 0.f};
      int pc = c4 - kbase;
      if (pc >= 0 && pc < KT) {
        ushort4 t = *(const ushort4*)&Pb[r * KT + pc];
        v[0] = bf2f(t.x); v[1] = bf2f(t.y); v[2] = bf2f(t.z); v[3] = bf2f(t.w);
      }
      __builtin_nontemporal_store(v, (f32x4*)&attnw[rowoff + c4]);
    }
  }
}

extern "C" void kernel_launch(void* const* d_in, const int* in_sizes, int n_in,
                              void* d_out, int out_size, void* d_ws, size_t ws_size,
                              hipStream_t stream) {
  const float* hs    = (const float*)d_in[0];
  const float* Wqkv  = (const float*)d_in[1];
  const float* bqkv  = (const float*)d_in[2];
  const float* Wproj = (const float*)d_in[3];
  const float* bproj = (const float*)d_in[4];
  const int*   wszp  = (const int*)d_in[5];

  float* out   = (float*)d_out;
  float* attnw = (float*)d_out + (size_t)BB * LL * DM;

  // workspace (60 MiB of 64):
  //   qkvb  bf16 [4096,3072] : 25165824 B
  //   hsctx bf16 [4096,1024] :  8388608 B (hs_bf16, later ctx_bf16)
  //   WqkvT bf16 [3072,1024] :  6291456 B
  //   WprojT bf16 [1024,1024]:  2097152 B
  //   band  bf16 [2048,32,160]: 20971520 B
  char* wsb = (char*)d_ws;
  uint16_t* qkvb   = (uint16_t*)wsb;
  uint16_t* hsctxb = (uint16_t*)(wsb + 25165824);
  uint16_t* WqkvT  = (uint16_t*)(wsb + 25165824 + 8388608);
  uint16_t* WprojT = (uint16_t*)(wsb + 25165824 + 8388608 + 6291456);
  uint16_t* band   = (uint16_t*)(wsb + 25165824 + 8388608 + 6291456 + 2097152);

  dim3 blk(256);

  cvt_bf16<<<dim3((BB * LL * DM / 4 + 255) / 256), blk, 0, stream>>>(hs, hsctxb, BB * LL * DM / 4);
  transpose_cvt<<<dim3(3 * DM / 32, DM / 32), blk, 0, stream>>>(Wqkv, WqkvT, DM, 3 * DM);
  transpose_cvt<<<dim3(DM / 32, DM / 32), blk, 0, stream>>>(Wproj, WprojT, DM, DM);

  // QKV projection -> bf16 qkv
  gemm_bt_bf16<<<dim3(3 * DM / 128, BB * LL / 128), blk, 0, stream>>>(
      hsctxb, WqkvT, bqkv, qkvb, 1, BB * LL, 3 * DM, DM);

  attn_compute<<<dim3(BB * NH * (LL / QT)), blk, 0, stream>>>(qkvb, band, hsctxb, wszp);

  // output projection (fp32 out)
  gemm_bt_bf16<<<dim3(DM / 128, BB * LL / 128), blk, 0, stream>>>(
      hsctxb, WprojT, bproj, out, 0, BB * LL, DM, DM);

  // stream the big attnw write last, at max store pressure
  expand_attnw<<<dim3(BB * NH * (LL / QT)), blk, 0, stream>>>(band, attnw, wszp);
}